// Round 1
// baseline (415.367 us; speedup 1.0000x reference)
//
#include <hip/hip_runtime.h>
#include <hip/hip_bf16.h>
#include <math.h>

#define N_NODES 16000
#define E_EDGES 256000
#define DIM 128
#define HEADS 4
#define LRELU_ALPHA 0.2f

// ---------------- generic fp32 tiled GEMM: C = A(MxK) * B(KxN) ----------------
#define BM 64
#define BN 64
#define BK 16

__global__ __launch_bounds__(256) void gemm_f32(
    const float* __restrict__ A, const float* __restrict__ B, float* __restrict__ C,
    int K, int lda, int ldb, int ldc,
    long a_zs, long b_zs, long c_zs)
{
    A += (long)blockIdx.z * a_zs;
    B += (long)blockIdx.z * b_zs;
    C += (long)blockIdx.z * c_zs;
    __shared__ __align__(16) float As[BK][BM + 4];
    __shared__ __align__(16) float Bs[BK][BN + 4];
    const int tid = threadIdx.x;
    const int tx = tid & 15;
    const int ty = tid >> 4;
    const int row0 = blockIdx.y * BM;
    const int col0 = blockIdx.x * BN;
    const int a_row = tid >> 2;          // 0..63
    const int a_k   = (tid & 3) << 2;    // 0,4,8,12
    const int b_k   = tid >> 4;          // 0..15
    const int b_n   = (tid & 15) << 2;   // 0..60
    float acc[4][4] = {};
    for (int k0 = 0; k0 < K; k0 += BK) {
        float4 av = *(const float4*)(A + (long)(row0 + a_row) * lda + (k0 + a_k));
        As[a_k + 0][a_row] = av.x;
        As[a_k + 1][a_row] = av.y;
        As[a_k + 2][a_row] = av.z;
        As[a_k + 3][a_row] = av.w;
        *(float4*)(&Bs[b_k][b_n]) = *(const float4*)(B + (long)(k0 + b_k) * ldb + (col0 + b_n));
        __syncthreads();
        #pragma unroll
        for (int kk = 0; kk < BK; ++kk) {
            float a4[4], b4[4];
            #pragma unroll
            for (int i = 0; i < 4; ++i) a4[i] = As[kk][(ty << 2) + i];
            #pragma unroll
            for (int j = 0; j < 4; ++j) b4[j] = Bs[kk][(tx << 2) + j];
            #pragma unroll
            for (int i = 0; i < 4; ++i)
                #pragma unroll
                for (int j = 0; j < 4; ++j)
                    acc[i][j] = fmaf(a4[i], b4[j], acc[i][j]);
        }
        __syncthreads();
    }
    #pragma unroll
    for (int i = 0; i < 4; ++i) {
        float* crow = C + (long)(row0 + (ty << 2) + i) * ldc + col0 + (tx << 2);
        #pragma unroll
        for (int j = 0; j < 4; ++j) crow[j] = acc[i][j];
    }
}

// ---------------- transpose: in (R x C) -> out (C x R) ----------------
__global__ void transpose_f32(const float* __restrict__ in, float* __restrict__ out, int R, int C)
{
    int idx = blockIdx.x * blockDim.x + threadIdx.x;
    if (idx >= R * C) return;
    int r = idx / C, c = idx % C;
    out[c * R + r] = in[idx];
}

// ---------------- wa[h][k] = sum_e W[h][k][e] * a{1,2}[h][e] ----------------
__global__ void wa_kernel(const float* __restrict__ W, const float* __restrict__ a,
                          float* __restrict__ wa1, float* __restrict__ wa2)
{
    int t = blockIdx.x * blockDim.x + threadIdx.x;
    if (t >= HEADS * DIM) return;
    int h = t >> 7, k = t & 127;
    const float* wrow = W + ((long)h * DIM + k) * DIM;
    const float* a1 = a + h * 2 * DIM;
    const float* a2 = a1 + DIM;
    float s1 = 0.f, s2 = 0.f;
    for (int e = 0; e < DIM; ++e) {
        float w = wrow[e];
        s1 = fmaf(w, a1[e], s1);
        s2 = fmaf(w, a2[e], s2);
    }
    wa1[t] = s1;
    wa2[t] = s2;
}

// ---------------- s_src[n,h] = h[n,:] . wa1[h,:]; s_dst likewise ----------------
__global__ __launch_bounds__(256) void s_kernel(const float* __restrict__ hin,
    const float* __restrict__ wa1, const float* __restrict__ wa2,
    float* __restrict__ s_src, float* __restrict__ s_dst)
{
    int wid  = blockIdx.x * 4 + (threadIdx.x >> 6);  // global wave id over N*H
    int lane = threadIdx.x & 63;
    int n = wid >> 2, hh = wid & 3;
    float h0 = hin[(long)n * DIM + lane];
    float h1 = hin[(long)n * DIM + 64 + lane];
    const float* w1 = wa1 + hh * DIM;
    const float* w2 = wa2 + hh * DIM;
    float p = h0 * w1[lane] + h1 * w1[64 + lane];
    float q = h0 * w2[lane] + h1 * w2[64 + lane];
    #pragma unroll
    for (int off = 32; off > 0; off >>= 1) {
        p += __shfl_down(p, off, 64);
        q += __shfl_down(q, off, 64);
    }
    if (lane == 0) { s_src[wid] = p; s_dst[wid] = q; }
}

// ---------------- CSR build ----------------
__global__ void deg_kernel(const int* __restrict__ dst, int* __restrict__ deg)
{
    int e = blockIdx.x * blockDim.x + threadIdx.x;
    if (e < E_EDGES) atomicAdd(&deg[dst[e]], 1);
}

__global__ __launch_bounds__(1024) void scan_kernel(const int* __restrict__ deg,
    int* __restrict__ offsets, int* __restrict__ cursor)
{
    __shared__ int buf[1024];
    __shared__ int carry;
    const int tid = threadIdx.x;
    if (tid == 0) carry = 0;
    __syncthreads();
    for (int base = 0; base < N_NODES; base += 1024) {
        int i = base + tid;
        int v = (i < N_NODES) ? deg[i] : 0;
        buf[tid] = v;
        __syncthreads();
        for (int off = 1; off < 1024; off <<= 1) {
            int t = (tid >= off) ? buf[tid - off] : 0;
            __syncthreads();
            buf[tid] += t;
            __syncthreads();
        }
        int incl = buf[tid] + carry;
        int excl = incl - v;
        if (i < N_NODES) { offsets[i] = excl; cursor[i] = excl; }
        int total = buf[1023];
        __syncthreads();
        if (tid == 0) carry += total;
        __syncthreads();
    }
    if (tid == 0) offsets[N_NODES] = carry;
}

__global__ void scatter_kernel(const int* __restrict__ src, const int* __restrict__ dst,
                               int* __restrict__ cursor, int* __restrict__ ssorted)
{
    int e = blockIdx.x * blockDim.x + threadIdx.x;
    if (e < E_EDGES) {
        int pos = atomicAdd(&cursor[dst[e]], 1);
        ssorted[pos] = src[e];
    }
}

// ---------------- fused softmax + gather aggregation (block per node) ----------------
__global__ __launch_bounds__(256) void aggregate_kernel(
    const float* __restrict__ Wh, const float* __restrict__ s_src,
    const float* __restrict__ s_dst, const int* __restrict__ offsets,
    const int* __restrict__ srcs, float* __restrict__ x)
{
    int n = blockIdx.x;
    int tid = threadIdx.x;
    int start = offsets[n], end = offsets[n + 1];
    int deg = end - start;
    long xo = (long)n * (HEADS * DIM);
    if (deg == 0) { x[xo + tid] = 0.f; x[xo + 256 + tid] = 0.f; return; }

    __shared__ float sdst[HEADS], sm[HEADS], sinv[HEADS];
    __shared__ float red[256];
    __shared__ int   ssrc[64];
    __shared__ float attl[64][HEADS];

    if (tid < HEADS) sdst[tid] = s_dst[n * HEADS + tid];
    __syncthreads();

    // pass 1: per-head max
    float mx[HEADS] = {-INFINITY, -INFINITY, -INFINITY, -INFINITY};
    for (int i = tid; i < deg; i += 256) {
        int s = srcs[start + i];
        #pragma unroll
        for (int h = 0; h < HEADS; ++h) {
            float e = s_src[s * HEADS + h] + sdst[h];
            e = e > 0.f ? e : LRELU_ALPHA * e;
            mx[h] = fmaxf(mx[h], e);
        }
    }
    #pragma unroll
    for (int h = 0; h < HEADS; ++h) {
        red[tid] = mx[h]; __syncthreads();
        for (int sdn = 128; sdn > 0; sdn >>= 1) {
            if (tid < sdn) red[tid] = fmaxf(red[tid], red[tid + sdn]);
            __syncthreads();
        }
        if (tid == 0) sm[h] = red[0];
        __syncthreads();
    }
    // pass 2: per-head denom
    float dn[HEADS] = {0.f, 0.f, 0.f, 0.f};
    for (int i = tid; i < deg; i += 256) {
        int s = srcs[start + i];
        #pragma unroll
        for (int h = 0; h < HEADS; ++h) {
            float e = s_src[s * HEADS + h] + sdst[h];
            e = e > 0.f ? e : LRELU_ALPHA * e;
            dn[h] += __expf(e - sm[h]);
        }
    }
    #pragma unroll
    for (int h = 0; h < HEADS; ++h) {
        red[tid] = dn[h]; __syncthreads();
        for (int sdn = 128; sdn > 0; sdn >>= 1) {
            if (tid < sdn) red[tid] += red[tid + sdn];
            __syncthreads();
        }
        if (tid == 0) sinv[h] = 1.f / red[0];
        __syncthreads();
    }
    // pass 3: weighted accumulation; thread owns dims tid and tid+256 of 512
    float acc0 = 0.f, acc1 = 0.f;
    const int h0 = tid >> 7;      // head for dim tid (0 or 1)
    const int h1 = h0 + 2;        // head for dim tid+256 (2 or 3)
    for (int cb = 0; cb < deg; cb += 64) {
        int clen = min(64, deg - cb);
        if (tid < clen) ssrc[tid] = srcs[start + cb + tid];
        __syncthreads();
        {
            int j = tid >> 2, h = tid & 3;
            if (j < clen) {
                int s = ssrc[j];
                float e = s_src[s * HEADS + h] + sdst[h];
                e = e > 0.f ? e : LRELU_ALPHA * e;
                attl[j][h] = __expf(e - sm[h]) * sinv[h];
            }
        }
        __syncthreads();
        for (int jj = 0; jj < clen; ++jj) {
            int s = ssrc[jj];
            const float* wr = Wh + (long)s * (HEADS * DIM);
            acc0 = fmaf(attl[jj][h0], wr[tid], acc0);
            acc1 = fmaf(attl[jj][h1], wr[256 + tid], acc1);
        }
        __syncthreads();
    }
    x[xo + tid] = acc0;
    x[xo + 256 + tid] = acc1;
}

// ---------------- GRU elementwise ----------------
__global__ void gru_kernel(const float* __restrict__ gi, const float* __restrict__ gh,
                           const float* __restrict__ b_ih, const float* __restrict__ b_hh,
                           const float* __restrict__ hin, float* __restrict__ out)
{
    int idx = blockIdx.x * blockDim.x + threadIdx.x;
    if (idx >= N_NODES * DIM) return;
    int n = idx >> 7, d = idx & 127;
    long g = (long)n * 384;
    float ir  = gi[g + d]        + b_ih[d];
    float iz  = gi[g + 128 + d]  + b_ih[128 + d];
    float in_ = gi[g + 256 + d]  + b_ih[256 + d];
    float hr  = gh[g + d]        + b_hh[d];
    float hz  = gh[g + 128 + d]  + b_hh[128 + d];
    float hn  = gh[g + 256 + d]  + b_hh[256 + d];
    float r = 1.f / (1.f + __expf(-(ir + hr)));
    float z = 1.f / (1.f + __expf(-(iz + hz)));
    float nv = tanhf(in_ + r * hn);
    out[idx] = (1.f - z) * nv + z * hin[idx];
}

extern "C" void kernel_launch(void* const* d_in, const int* in_sizes, int n_in,
                              void* d_out, int out_size, void* d_ws, size_t ws_size,
                              hipStream_t stream)
{
    const float* h    = (const float*)d_in[0];
    const float* W    = (const float*)d_in[1];
    const float* a    = (const float*)d_in[2];
    const float* W_ih = (const float*)d_in[3];
    const float* W_hh = (const float*)d_in[4];
    const float* b_ih = (const float*)d_in[5];
    const float* b_hh = (const float*)d_in[6];
    const int*   src  = (const int*)d_in[7];
    const int*   dst  = (const int*)d_in[8];
    float* out = (float*)d_out;

    char* ws = (char*)d_ws;
    size_t off = 0;
    auto alloc = [&](size_t bytes) { void* p = ws + off; off += (bytes + 255) & ~(size_t)255; return p; };

    float* Wh    = (float*)alloc((size_t)N_NODES * 512 * 4);   // reused as gi after aggregate
    float* x     = (float*)alloc((size_t)N_NODES * 512 * 4);   // reused as gh after gi GEMM
    float* Wiht  = (float*)alloc(512 * 384 * 4);
    float* Whht  = (float*)alloc(128 * 384 * 4);
    float* wa1   = (float*)alloc(512 * 4);
    float* wa2   = (float*)alloc(512 * 4);
    float* s_src = (float*)alloc((size_t)N_NODES * HEADS * 4);
    float* s_dst = (float*)alloc((size_t)N_NODES * HEADS * 4);
    int*   deg   = (int*)alloc((N_NODES + 1) * 4);
    int*   offs  = (int*)alloc((N_NODES + 1) * 4);
    int*   cur   = (int*)alloc(N_NODES * 4);
    int*   ssort = (int*)alloc((size_t)E_EDGES * 4);
    float* gi    = Wh;  // alias: Wh dead after aggregate
    float* gh    = x;   // alias: x dead after gi GEMM

    hipMemsetAsync(deg, 0, N_NODES * sizeof(int), stream);

    transpose_f32<<<(384 * 512 + 255) / 256, 256, 0, stream>>>(W_ih, Wiht, 384, 512);
    transpose_f32<<<(384 * 128 + 255) / 256, 256, 0, stream>>>(W_hh, Whht, 384, 128);
    wa_kernel<<<2, 256, 0, stream>>>(W, a, wa1, wa2);
    s_kernel<<<N_NODES, 256, 0, stream>>>(h, wa1, wa2, s_src, s_dst);

    deg_kernel<<<(E_EDGES + 255) / 256, 256, 0, stream>>>(dst, deg);
    scan_kernel<<<1, 1024, 0, stream>>>(deg, offs, cur);
    scatter_kernel<<<(E_EDGES + 255) / 256, 256, 0, stream>>>(src, dst, cur, ssort);

    // Wh[n,h,:] = h[n,:] @ W[h]  (C row stride 512, head offset 128)
    dim3 gWh(2, 250, 4);
    gemm_f32<<<gWh, 256, 0, stream>>>(h, W, Wh, 128, 128, 128, 512,
                                      0L, (long)DIM * DIM, (long)DIM);

    aggregate_kernel<<<N_NODES, 256, 0, stream>>>(Wh, s_src, s_dst, offs, ssort, x);

    // gi = x (N x 512) @ Wiht (512 x 384)
    dim3 gGi(6, 250, 1);
    gemm_f32<<<gGi, 256, 0, stream>>>(x, Wiht, gi, 512, 512, 384, 384, 0L, 0L, 0L);
    // gh = h (N x 128) @ Whht (128 x 384)
    gemm_f32<<<gGi, 256, 0, stream>>>(h, Whht, gh, 128, 128, 384, 384, 0L, 0L, 0L);

    gru_kernel<<<(N_NODES * DIM + 255) / 256, 256, 0, stream>>>(gi, gh, b_ih, b_hh, h, out);
}

// Round 2
// 230.429 us; speedup vs baseline: 1.8026x; 1.8026x over previous
//
#include <hip/hip_runtime.h>
#include <math.h>

#define N_NODES 16000
#define E_EDGES 256000
#define DIM 128
#define HEADS 4
#define LRELU_ALPHA 0.2f

typedef unsigned short u16;
typedef unsigned int u32;
typedef short bf16x8 __attribute__((ext_vector_type(8)));
typedef float floatx4 __attribute__((ext_vector_type(4)));

#define AS1 __attribute__((address_space(1)))
#define AS3 __attribute__((address_space(3)))

__device__ __forceinline__ u16 f2bf(float f) {
    u32 u = __float_as_uint(f);
    u32 r = (u + 0x7fffu + ((u >> 16) & 1u)) >> 16;   // RNE
    return (u16)r;
}

// ---------- fused fp32->bf16 casts for h, W_ih, W_hh ----------
__global__ void cvt3_kernel(const float* __restrict__ s0, u16* __restrict__ d0, int n0,
                            const float* __restrict__ s1, u16* __restrict__ d1, int n1,
                            const float* __restrict__ s2, u16* __restrict__ d2, int n2)
{
    int i = blockIdx.x * blockDim.x + threadIdx.x;
    if (i < n0) d0[i] = f2bf(s0[i]);
    if (i < n1) d1[i] = f2bf(s1[i]);
    if (i < n2) d2[i] = f2bf(s2[i]);
}

// ---------- Wt[(h*128+e)][d] = W[h][d][e], bf16 ----------
__global__ void cvt_wt_kernel(const float* __restrict__ W, u16* __restrict__ Wt)
{
    int t = blockIdx.x * blockDim.x + threadIdx.x;   // 65536
    int r = t >> 7, d = t & 127;
    int h = r >> 7, e = r & 127;
    Wt[t] = f2bf(W[(h * 128 + d) * 128 + e]);
}

// ---------- wa[h][k] = sum_e W[h][k][e] * a{1,2}[h][e] ----------
__global__ void wa_kernel(const float* __restrict__ W, const float* __restrict__ a,
                          float* __restrict__ wa1, float* __restrict__ wa2)
{
    int t = blockIdx.x * blockDim.x + threadIdx.x;
    if (t >= HEADS * DIM) return;
    int h = t >> 7, k = t & 127;
    const float* wrow = W + ((long)h * DIM + k) * DIM;
    const float* a1 = a + h * 2 * DIM;
    const float* a2 = a1 + DIM;
    float s1 = 0.f, s2 = 0.f;
    for (int e = 0; e < DIM; ++e) {
        float w = wrow[e];
        s1 = fmaf(w, a1[e], s1);
        s2 = fmaf(w, a2[e], s2);
    }
    wa1[t] = s1;
    wa2[t] = s2;
}

// ---------- s_src[n,h] = h[n,:].wa1[h,:]; s_dst likewise ----------
__global__ __launch_bounds__(256) void s_kernel(const float* __restrict__ hin,
    const float* __restrict__ wa1, const float* __restrict__ wa2,
    float* __restrict__ s_src, float* __restrict__ s_dst)
{
    int wid  = blockIdx.x * 4 + (threadIdx.x >> 6);
    int lane = threadIdx.x & 63;
    int n = wid >> 2, hh = wid & 3;
    float h0 = hin[(long)n * DIM + lane];
    float h1 = hin[(long)n * DIM + 64 + lane];
    const float* w1 = wa1 + hh * DIM;
    const float* w2 = wa2 + hh * DIM;
    float p = h0 * w1[lane] + h1 * w1[64 + lane];
    float q = h0 * w2[lane] + h1 * w2[64 + lane];
    #pragma unroll
    for (int off = 32; off > 0; off >>= 1) {
        p += __shfl_down(p, off, 64);
        q += __shfl_down(q, off, 64);
    }
    if (lane == 0) { s_src[wid] = p; s_dst[wid] = q; }
}

// ---------- CSR build ----------
__global__ void deg_kernel(const int* __restrict__ dst, int* __restrict__ deg)
{
    int e = blockIdx.x * blockDim.x + threadIdx.x;
    if (e < E_EDGES) atomicAdd(&deg[dst[e]], 1);
}

__global__ __launch_bounds__(1024) void scan_kernel(const int* __restrict__ deg,
    int* __restrict__ offsets, int* __restrict__ cursor)
{
    __shared__ int wsum[16];
    __shared__ int carry_s;
    const int tid = threadIdx.x;
    const int lane = tid & 63;
    const int w = tid >> 6;
    if (tid == 0) carry_s = 0;
    __syncthreads();
    for (int base = 0; base < N_NODES; base += 1024) {
        int i = base + tid;
        int v = (i < N_NODES) ? deg[i] : 0;
        int x = v;
        #pragma unroll
        for (int off = 1; off < 64; off <<= 1) {
            int t = __shfl_up(x, off, 64);
            if (lane >= off) x += t;
        }
        if (lane == 63) wsum[w] = x;
        __syncthreads();
        if (w == 0) {
            int s = (lane < 16) ? wsum[lane] : 0;
            #pragma unroll
            for (int off = 1; off < 16; off <<= 1) {
                int t = __shfl_up(s, off, 64);
                if (lane >= off) s += t;
            }
            if (lane < 16) wsum[lane] = s;
        }
        __syncthreads();
        int wpre = (w == 0) ? 0 : wsum[w - 1];
        int incl = x + wpre + carry_s;
        if (i < N_NODES) { offsets[i] = incl - v; cursor[i] = incl - v; }
        __syncthreads();
        if (tid == 1023) carry_s = incl;
        __syncthreads();
    }
    if (tid == 0) offsets[N_NODES] = carry_s;
}

__global__ void scatter_kernel(const int* __restrict__ src, const int* __restrict__ dst,
                               int* __restrict__ cursor, int* __restrict__ ssorted)
{
    int e = blockIdx.x * blockDim.x + threadIdx.x;
    if (e < E_EDGES) {
        int pos = atomicAdd(&cursor[dst[e]], 1);
        ssorted[pos] = src[e];
    }
}

// ---------- bf16 MFMA TN GEMM: C(MxN) = A(MxK) * Bt(NxK)^T ----------
// 128x128 tile, BK=32, 4 waves (2x2 of 64x64), 16x16x32 MFMA.
template<int WRITE_BF16>
__global__ __launch_bounds__(256) void gemm_bt(
    const u16* __restrict__ A, const u16* __restrict__ Bt, void* __restrict__ Cv,
    int K, int ldc)
{
    __shared__ __align__(16) u16 Alds[128][32];
    __shared__ __align__(16) u16 Blds[128][32];
    const int tid  = threadIdx.x;
    const int wave = tid >> 6;
    const int lane = tid & 63;
    const int quad = lane >> 4;
    const int l15  = lane & 15;
    const int row0 = blockIdx.y * 128;
    const int col0 = blockIdx.x * 128;
    const int wm = (wave >> 1) * 64;
    const int wn = (wave & 1) * 64;
    const int ch0 = wave * 2;
    const int srow = lane >> 2;           // 0..15 within chunk
    const int scol = (lane & 3) * 8;      // k element offset

    floatx4 acc[4][4] = {};

    for (int k0 = 0; k0 < K; k0 += 32) {
        #pragma unroll
        for (int c = 0; c < 2; ++c) {
            int ch = ch0 + c;
            const u16* ga = A + (size_t)(row0 + ch * 16 + srow) * K + k0 + scol;
            __builtin_amdgcn_global_load_lds((AS1 void*)ga, (AS3 void*)&Alds[ch * 16][0], 16, 0, 0);
            const u16* gb = Bt + (size_t)(col0 + ch * 16 + srow) * K + k0 + scol;
            __builtin_amdgcn_global_load_lds((AS1 void*)gb, (AS3 void*)&Blds[ch * 16][0], 16, 0, 0);
        }
        __syncthreads();
        bf16x8 af[4], bfr[4];
        #pragma unroll
        for (int i = 0; i < 4; ++i) af[i] = *(const bf16x8*)&Alds[wm + i * 16 + l15][quad * 8];
        #pragma unroll
        for (int j = 0; j < 4; ++j) bfr[j] = *(const bf16x8*)&Blds[wn + j * 16 + l15][quad * 8];
        #pragma unroll
        for (int i = 0; i < 4; ++i)
            #pragma unroll
            for (int j = 0; j < 4; ++j)
                acc[i][j] = __builtin_amdgcn_mfma_f32_16x16x32_bf16(af[i], bfr[j], acc[i][j], 0, 0, 0);
        __syncthreads();
    }
    // epilogue: C/D layout col=lane&15, row=quad*4+reg
    #pragma unroll
    for (int i = 0; i < 4; ++i) {
        #pragma unroll
        for (int r = 0; r < 4; ++r) {
            int row = row0 + wm + i * 16 + quad * 4 + r;
            size_t base = (size_t)row * ldc + col0 + wn + l15;
            if (WRITE_BF16) {
                u16* C = (u16*)Cv;
                #pragma unroll
                for (int j = 0; j < 4; ++j) C[base + j * 16] = f2bf(acc[i][j][r]);
            } else {
                float* C = (float*)Cv;
                #pragma unroll
                for (int j = 0; j < 4; ++j) C[base + j * 16] = acc[i][j][r];
            }
        }
    }
}

// ---------- single-pass fused softmax + gather aggregation ----------
// scores are O(1): exp without max-subtraction is safe; x = sum(exp*Wh)/sum(exp)
__global__ __launch_bounds__(256) void aggregate_kernel(
    const u16* __restrict__ Whb, const float* __restrict__ s_src,
    const float* __restrict__ s_dst, const int* __restrict__ offsets,
    const int* __restrict__ srcs, u16* __restrict__ xb)
{
    const int n = blockIdx.x;
    const int tid = threadIdx.x;
    const int start = offsets[n];
    const int deg = offsets[n + 1] - start;
    u32* xrow = (u32*)(xb + (size_t)n * 512);
    if (deg == 0) { xrow[tid] = 0u; return; }

    __shared__ float sdst[HEADS];
    __shared__ float attl[64][HEADS];
    __shared__ int ssrc[64];
    __shared__ float red[256];

    if (tid < HEADS) sdst[tid] = s_dst[n * HEADS + tid];
    __syncthreads();

    const int j  = tid >> 2;       // edge slot for score compute
    const int hh = tid & 3;        // head for score compute
    const int ht = tid >> 6;       // head for owned dims {2t,2t+1}
    const u32* wb = (const u32*)Whb;
    float acc0 = 0.f, acc1 = 0.f, dsum = 0.f;

    for (int cb = 0; cb < deg; cb += 64) {
        int clen = min(64, deg - cb);
        if (tid < clen) ssrc[tid] = srcs[start + cb + tid];
        __syncthreads();
        if (j < clen) {
            int s = ssrc[j];
            float e = s_src[s * HEADS + hh] + sdst[hh];
            e = e > 0.f ? e : LRELU_ALPHA * e;
            float w = __expf(e);
            attl[j][hh] = w;
            dsum += w;
        }
        __syncthreads();
        int jj = 0;
        for (; jj + 4 <= clen; jj += 4) {
            int s0 = ssrc[jj], s1 = ssrc[jj + 1], s2 = ssrc[jj + 2], s3 = ssrc[jj + 3];
            u32 v0 = wb[(s0 << 8) + tid];
            u32 v1 = wb[(s1 << 8) + tid];
            u32 v2 = wb[(s2 << 8) + tid];
            u32 v3 = wb[(s3 << 8) + tid];
            float w0 = attl[jj][ht], w1 = attl[jj + 1][ht];
            float w2 = attl[jj + 2][ht], w3 = attl[jj + 3][ht];
            acc0 = fmaf(w0, __uint_as_float(v0 << 16), acc0);
            acc1 = fmaf(w0, __uint_as_float(v0 & 0xffff0000u), acc1);
            acc0 = fmaf(w1, __uint_as_float(v1 << 16), acc0);
            acc1 = fmaf(w1, __uint_as_float(v1 & 0xffff0000u), acc1);
            acc0 = fmaf(w2, __uint_as_float(v2 << 16), acc0);
            acc1 = fmaf(w2, __uint_as_float(v2 & 0xffff0000u), acc1);
            acc0 = fmaf(w3, __uint_as_float(v3 << 16), acc0);
            acc1 = fmaf(w3, __uint_as_float(v3 & 0xffff0000u), acc1);
        }
        for (; jj < clen; ++jj) {
            int s = ssrc[jj];
            u32 v = wb[(s << 8) + tid];
            float w = attl[jj][ht];
            acc0 = fmaf(w, __uint_as_float(v << 16), acc0);
            acc1 = fmaf(w, __uint_as_float(v & 0xffff0000u), acc1);
        }
        __syncthreads();
    }
    red[tid] = dsum;
    __syncthreads();
    for (int off = 128; off >= 4; off >>= 1) {
        if (tid < off) red[tid] += red[tid + off];
        __syncthreads();
    }
    float invd = 1.f / red[ht];
    xrow[tid] = (u32)f2bf(acc0 * invd) | ((u32)f2bf(acc1 * invd) << 16);
}

// ---------- GRU elementwise ----------
__global__ void gru_kernel(const float* __restrict__ gi, const float* __restrict__ gh,
                           const float* __restrict__ b_ih, const float* __restrict__ b_hh,
                           const float* __restrict__ hin, float* __restrict__ out)
{
    int idx = blockIdx.x * blockDim.x + threadIdx.x;
    if (idx >= N_NODES * DIM) return;
    int n = idx >> 7, d = idx & 127;
    long g = (long)n * 384;
    float ir  = gi[g + d]       + b_ih[d];
    float iz  = gi[g + 128 + d] + b_ih[128 + d];
    float in_ = gi[g + 256 + d] + b_ih[256 + d];
    float hr  = gh[g + d]       + b_hh[d];
    float hz  = gh[g + 128 + d] + b_hh[128 + d];
    float hn  = gh[g + 256 + d] + b_hh[256 + d];
    float r = 1.f / (1.f + __expf(-(ir + hr)));
    float z = 1.f / (1.f + __expf(-(iz + hz)));
    float nv = tanhf(in_ + r * hn);
    out[idx] = (1.f - z) * nv + z * hin[idx];
}

extern "C" void kernel_launch(void* const* d_in, const int* in_sizes, int n_in,
                              void* d_out, int out_size, void* d_ws, size_t ws_size,
                              hipStream_t stream)
{
    const float* h    = (const float*)d_in[0];
    const float* W    = (const float*)d_in[1];
    const float* a    = (const float*)d_in[2];
    const float* W_ih = (const float*)d_in[3];
    const float* W_hh = (const float*)d_in[4];
    const float* b_ih = (const float*)d_in[5];
    const float* b_hh = (const float*)d_in[6];
    const int*   src  = (const int*)d_in[7];
    const int*   dst  = (const int*)d_in[8];
    float* out = (float*)d_out;

    char* ws = (char*)d_ws;
    size_t off = 0;
    auto alloc = [&](size_t bytes) { void* p = ws + off; off += (bytes + 255) & ~(size_t)255; return p; };

    u16*   Whb  = (u16*)alloc((size_t)N_NODES * 512 * 2);
    u16*   xb   = (u16*)alloc((size_t)N_NODES * 512 * 2);
    float* gi   = (float*)alloc((size_t)N_NODES * 384 * 4);
    float* gh   = (float*)alloc((size_t)N_NODES * 384 * 4);
    u16*   hbf  = (u16*)alloc((size_t)N_NODES * 128 * 2);
    u16*   Wt   = (u16*)alloc(512 * 128 * 2);
    u16*   Wihb = (u16*)alloc(384 * 512 * 2);
    u16*   Whhb = (u16*)alloc(384 * 128 * 2);
    float* wa1  = (float*)alloc(512 * 4);
    float* wa2  = (float*)alloc(512 * 4);
    float* s_src = (float*)alloc((size_t)N_NODES * HEADS * 4);
    float* s_dst = (float*)alloc((size_t)N_NODES * HEADS * 4);
    int*   deg  = (int*)alloc((N_NODES + 1) * 4);
    int*   offs = (int*)alloc((N_NODES + 1) * 4);
    int*   cur  = (int*)alloc(N_NODES * 4);
    int*   ssort = (int*)alloc((size_t)E_EDGES * 4);

    hipMemsetAsync(deg, 0, N_NODES * sizeof(int), stream);

    cvt3_kernel<<<(N_NODES * 128 + 255) / 256, 256, 0, stream>>>(
        h, hbf, N_NODES * 128, W_ih, Wihb, 384 * 512, W_hh, Whhb, 384 * 128);
    cvt_wt_kernel<<<256, 256, 0, stream>>>(W, Wt);
    wa_kernel<<<2, 256, 0, stream>>>(W, a, wa1, wa2);
    s_kernel<<<N_NODES, 256, 0, stream>>>(h, wa1, wa2, s_src, s_dst);

    deg_kernel<<<(E_EDGES + 255) / 256, 256, 0, stream>>>(dst, deg);
    scan_kernel<<<1, 1024, 0, stream>>>(deg, offs, cur);
    scatter_kernel<<<(E_EDGES + 255) / 256, 256, 0, stream>>>(src, dst, cur, ssort);

    // Wh (16000x512) = h (16000x128) @ Wt(512x128)^T, bf16 out
    gemm_bt<1><<<dim3(4, 125), 256, 0, stream>>>(hbf, Wt, Whb, 128, 512);

    aggregate_kernel<<<N_NODES, 256, 0, stream>>>(Whb, s_src, s_dst, offs, ssort, xb);

    // gi (16000x384) = x (16000x512) @ W_ih(384x512)^T, f32 out
    gemm_bt<0><<<dim3(3, 125), 256, 0, stream>>>(xb, Wihb, gi, 512, 384);
    // gh (16000x384) = h (16000x128) @ W_hh(384x128)^T, f32 out
    gemm_bt<0><<<dim3(3, 125), 256, 0, stream>>>(hbf, Whhb, gh, 128, 384);

    gru_kernel<<<(N_NODES * DIM + 255) / 256, 256, 0, stream>>>(gi, gh, b_ih, b_hh, h, out);
}

// Round 3
// 209.747 us; speedup vs baseline: 1.9803x; 1.0986x over previous
//
#include <hip/hip_runtime.h>
#include <math.h>

#define N_NODES 16000
#define E_EDGES 256000
#define DIM 128
#define HEADS 4
#define LRELU_ALPHA 0.2f

typedef unsigned short u16;
typedef unsigned int u32;
typedef short bf16x8 __attribute__((ext_vector_type(8)));
typedef float floatx4 __attribute__((ext_vector_type(4)));

#define AS1 __attribute__((address_space(1)))
#define AS3 __attribute__((address_space(3)))

__device__ __forceinline__ u16 f2bf(float f) {
    u32 u = __float_as_uint(f);
    u32 r = (u + 0x7fffu + ((u >> 16) & 1u)) >> 16;   // RNE
    return (u16)r;
}

// ---------- fp32->bf16 casts for W_ih, W_hh, W ----------
__global__ void cvt3_kernel(const float* __restrict__ s0, u16* __restrict__ d0, int n0,
                            const float* __restrict__ s1, u16* __restrict__ d1, int n1,
                            const float* __restrict__ s2, u16* __restrict__ d2, int n2)
{
    int i = blockIdx.x * blockDim.x + threadIdx.x;
    if (i < n0) d0[i] = f2bf(s0[i]);
    if (i < n1) d1[i] = f2bf(s1[i]);
    if (i < n2) d2[i] = f2bf(s2[i]);
}

// ---------- wa[h][k] = sum_e W[h][k][e] * a{1,2}[h][e] ----------
__global__ void wa_kernel(const float* __restrict__ W, const float* __restrict__ a,
                          float* __restrict__ wa1, float* __restrict__ wa2)
{
    int t = blockIdx.x * blockDim.x + threadIdx.x;
    if (t >= HEADS * DIM) return;
    int h = t >> 7, k = t & 127;
    const float* wrow = W + ((long)h * DIM + k) * DIM;
    const float* a1 = a + h * 2 * DIM;
    const float* a2 = a1 + DIM;
    float s1 = 0.f, s2 = 0.f;
    for (int e = 0; e < DIM; ++e) {
        float w = wrow[e];
        s1 = fmaf(w, a1[e], s1);
        s2 = fmaf(w, a2[e], s2);
    }
    wa1[t] = s1;
    wa2[t] = s2;
}

// ---------- s_src/s_dst + fused h->bf16 cast ----------
__global__ __launch_bounds__(256) void s_kernel(const float* __restrict__ hin,
    const float* __restrict__ wa1, const float* __restrict__ wa2,
    float* __restrict__ s_src, float* __restrict__ s_dst, u16* __restrict__ hbf)
{
    int wid  = blockIdx.x * 4 + (threadIdx.x >> 6);
    int lane = threadIdx.x & 63;
    int n = wid >> 2, hh = wid & 3;
    float h0 = hin[(long)n * DIM + lane];
    float h1 = hin[(long)n * DIM + 64 + lane];
    if (hh == 0) {
        hbf[(long)n * DIM + lane] = f2bf(h0);
        hbf[(long)n * DIM + 64 + lane] = f2bf(h1);
    }
    const float* w1 = wa1 + hh * DIM;
    const float* w2 = wa2 + hh * DIM;
    float p = h0 * w1[lane] + h1 * w1[64 + lane];
    float q = h0 * w2[lane] + h1 * w2[64 + lane];
    #pragma unroll
    for (int off = 32; off > 0; off >>= 1) {
        p += __shfl_down(p, off, 64);
        q += __shfl_down(q, off, 64);
    }
    if (lane == 0) { s_src[wid] = p; s_dst[wid] = q; }
}

// ---------- CSR build ----------
__global__ void deg_kernel(const int* __restrict__ dst, int* __restrict__ deg)
{
    int e = blockIdx.x * blockDim.x + threadIdx.x;
    if (e < E_EDGES) atomicAdd(&deg[dst[e]], 1);
}

// 4 nodes/thread, shfl-based block scan over 16000 entries
__global__ __launch_bounds__(1024) void scan_kernel(const int* __restrict__ deg,
    int* __restrict__ offsets, int* __restrict__ cursor)
{
    __shared__ int wsum[16];
    __shared__ int carry_s;
    const int tid = threadIdx.x;
    const int lane = tid & 63;
    const int w = tid >> 6;
    if (tid == 0) carry_s = 0;
    __syncthreads();
    const int4* deg4 = (const int4*)deg;
    const int N4 = N_NODES / 4;   // 4000
    for (int base = 0; base < N4; base += 1024) {
        int i = base + tid;
        int4 v = (i < N4) ? deg4[i] : int4{0, 0, 0, 0};
        int p1 = v.x + v.y;
        int p2 = p1 + v.z;
        int tot = p2 + v.w;
        int x = tot;
        #pragma unroll
        for (int off = 1; off < 64; off <<= 1) {
            int t = __shfl_up(x, off, 64);
            if (lane >= off) x += t;
        }
        if (lane == 63) wsum[w] = x;
        __syncthreads();
        if (w == 0) {
            int s = (lane < 16) ? wsum[lane] : 0;
            #pragma unroll
            for (int off = 1; off < 16; off <<= 1) {
                int t = __shfl_up(s, off, 64);
                if (lane >= off) s += t;
            }
            if (lane < 16) wsum[lane] = s;
        }
        __syncthreads();
        int excl = x - tot + ((w == 0) ? 0 : wsum[w - 1]) + carry_s;
        if (i < N4) {
            int4 o = {excl, excl + v.x, excl + p1, excl + p2};
            ((int4*)offsets)[i] = o;
            ((int4*)cursor)[i] = o;
        }
        int incl = excl + tot;
        __syncthreads();
        if (tid == 1023) carry_s = incl;
        __syncthreads();
    }
    if (tid == 0) offsets[N_NODES] = carry_s;
}

__global__ void scatter_kernel(const int* __restrict__ src, const int* __restrict__ dst,
                               int* __restrict__ cursor, int* __restrict__ ssorted)
{
    int e = blockIdx.x * blockDim.x + threadIdx.x;
    if (e < E_EDGES) {
        int pos = atomicAdd(&cursor[dst[e]], 1);
        ssorted[pos] = src[e];
    }
}

// ---------- bf16 MFMA TN GEMM: C(R x C) = A(R x K) * Bt(C x K)^T ----------
template<int WRITE_BF16>
__global__ __launch_bounds__(256) void gemm_bt(
    const u16* __restrict__ A, const u16* __restrict__ Bt, void* __restrict__ Cv,
    int K, int lda, int ldb, int ldc,
    long a_zoff, long b_zoff, long c_zoff)
{
    A  += (long)blockIdx.z * a_zoff;
    Bt += (long)blockIdx.z * b_zoff;
    __shared__ __align__(16) u16 Alds[128][32];
    __shared__ __align__(16) u16 Blds[128][32];
    const int tid  = threadIdx.x;
    const int wave = tid >> 6;
    const int lane = tid & 63;
    const int quad = lane >> 4;
    const int l15  = lane & 15;
    const int row0 = blockIdx.y * 128;
    const int col0 = blockIdx.x * 128;
    const int wm = (wave >> 1) * 64;
    const int wn = (wave & 1) * 64;
    const int ch0 = wave * 2;
    const int srow = lane >> 2;
    const int scol = (lane & 3) * 8;

    floatx4 acc[4][4] = {};

    for (int k0 = 0; k0 < K; k0 += 32) {
        #pragma unroll
        for (int c = 0; c < 2; ++c) {
            int ch = ch0 + c;
            const u16* ga = A + (size_t)(row0 + ch * 16 + srow) * lda + k0 + scol;
            __builtin_amdgcn_global_load_lds((AS1 void*)ga, (AS3 void*)&Alds[ch * 16][0], 16, 0, 0);
            const u16* gb = Bt + (size_t)(col0 + ch * 16 + srow) * ldb + k0 + scol;
            __builtin_amdgcn_global_load_lds((AS1 void*)gb, (AS3 void*)&Blds[ch * 16][0], 16, 0, 0);
        }
        __syncthreads();
        bf16x8 af[4], bfr[4];
        #pragma unroll
        for (int i = 0; i < 4; ++i) af[i] = *(const bf16x8*)&Alds[wm + i * 16 + l15][quad * 8];
        #pragma unroll
        for (int j = 0; j < 4; ++j) bfr[j] = *(const bf16x8*)&Blds[wn + j * 16 + l15][quad * 8];
        #pragma unroll
        for (int i = 0; i < 4; ++i)
            #pragma unroll
            for (int j = 0; j < 4; ++j)
                acc[i][j] = __builtin_amdgcn_mfma_f32_16x16x32_bf16(af[i], bfr[j], acc[i][j], 0, 0, 0);
        __syncthreads();
    }
    #pragma unroll
    for (int i = 0; i < 4; ++i) {
        #pragma unroll
        for (int r = 0; r < 4; ++r) {
            int row = row0 + wm + i * 16 + quad * 4 + r;
            size_t base = (size_t)row * ldc + col0 + wn + l15 + (size_t)blockIdx.z * c_zoff;
            if (WRITE_BF16) {
                u16* C = (u16*)Cv;
                #pragma unroll
                for (int j = 0; j < 4; ++j) C[base + j * 16] = f2bf(acc[i][j][r]);
            } else {
                float* C = (float*)Cv;
                #pragma unroll
                for (int j = 0; j < 4; ++j) C[base + j * 16] = acc[i][j][r];
            }
        }
    }
}

// ---------- single-pass fused softmax + h-gather aggregation ----------
__global__ __launch_bounds__(256) void aggregate_kernel(
    const u32* __restrict__ h32, const float* __restrict__ s_src,
    const float* __restrict__ s_dst, const int* __restrict__ offsets,
    const int* __restrict__ srcs, u16* __restrict__ hagg)
{
    const int n = blockIdx.x;
    const int tid = threadIdx.x;
    const int start = offsets[n];
    const int deg = offsets[n + 1] - start;
    u32* xrow = (u32*)(hagg + (size_t)n * 512);
    if (deg == 0) { xrow[tid] = 0u; return; }

    __shared__ float sdst[HEADS];
    __shared__ float attl[64][HEADS];
    __shared__ int ssrc[64];
    __shared__ float red[256];

    if (tid < HEADS) sdst[tid] = s_dst[n * HEADS + tid];
    __syncthreads();

    const int j  = tid >> 2;
    const int hh = tid & 3;
    const int ht = tid >> 6;
    const int dw = tid & 63;
    float acc0 = 0.f, acc1 = 0.f, dsum = 0.f;

    for (int cb = 0; cb < deg; cb += 64) {
        int clen = min(64, deg - cb);
        if (tid < clen) ssrc[tid] = srcs[start + cb + tid];
        __syncthreads();
        if (j < clen) {
            int s = ssrc[j];
            float e = s_src[s * HEADS + hh] + sdst[hh];
            e = e > 0.f ? e : LRELU_ALPHA * e;
            float w = __expf(e);
            attl[j][hh] = w;
            dsum += w;
        }
        __syncthreads();
        int jj = 0;
        for (; jj + 4 <= clen; jj += 4) {
            int s0 = ssrc[jj], s1 = ssrc[jj + 1], s2 = ssrc[jj + 2], s3 = ssrc[jj + 3];
            u32 v0 = h32[(s0 << 6) + dw];
            u32 v1 = h32[(s1 << 6) + dw];
            u32 v2 = h32[(s2 << 6) + dw];
            u32 v3 = h32[(s3 << 6) + dw];
            float w0 = attl[jj][ht], w1 = attl[jj + 1][ht];
            float w2 = attl[jj + 2][ht], w3 = attl[jj + 3][ht];
            acc0 = fmaf(w0, __uint_as_float(v0 << 16), acc0);
            acc1 = fmaf(w0, __uint_as_float(v0 & 0xffff0000u), acc1);
            acc0 = fmaf(w1, __uint_as_float(v1 << 16), acc0);
            acc1 = fmaf(w1, __uint_as_float(v1 & 0xffff0000u), acc1);
            acc0 = fmaf(w2, __uint_as_float(v2 << 16), acc0);
            acc1 = fmaf(w2, __uint_as_float(v2 & 0xffff0000u), acc1);
            acc0 = fmaf(w3, __uint_as_float(v3 << 16), acc0);
            acc1 = fmaf(w3, __uint_as_float(v3 & 0xffff0000u), acc1);
        }
        for (; jj < clen; ++jj) {
            int s = ssrc[jj];
            u32 v = h32[(s << 6) + dw];
            float w = attl[jj][ht];
            acc0 = fmaf(w, __uint_as_float(v << 16), acc0);
            acc1 = fmaf(w, __uint_as_float(v & 0xffff0000u), acc1);
        }
        __syncthreads();
    }
    red[tid] = dsum;
    __syncthreads();
    for (int off = 128; off >= 4; off >>= 1) {
        if (tid < off) red[tid] += red[tid + off];
        __syncthreads();
    }
    float invd = 1.f / red[ht];
    xrow[tid] = (u32)f2bf(acc0 * invd) | ((u32)f2bf(acc1 * invd) << 16);
}

// ---------- GRU elementwise ----------
__global__ void gru_kernel(const float* __restrict__ gi, const float* __restrict__ gh,
                           const float* __restrict__ b_ih, const float* __restrict__ b_hh,
                           const float* __restrict__ hin, float* __restrict__ out)
{
    int idx = blockIdx.x * blockDim.x + threadIdx.x;
    if (idx >= N_NODES * DIM) return;
    int n = idx >> 7, d = idx & 127;
    long g = (long)n * 384;
    float ir  = gi[g + d]       + b_ih[d];
    float iz  = gi[g + 128 + d] + b_ih[128 + d];
    float in_ = gi[g + 256 + d] + b_ih[256 + d];
    float hr  = gh[g + d]       + b_hh[d];
    float hz  = gh[g + 128 + d] + b_hh[128 + d];
    float hn  = gh[g + 256 + d] + b_hh[256 + d];
    float r = 1.f / (1.f + __expf(-(ir + hr)));
    float z = 1.f / (1.f + __expf(-(iz + hz)));
    float nv = tanhf(in_ + r * hn);
    out[idx] = (1.f - z) * nv + z * hin[idx];
}

extern "C" void kernel_launch(void* const* d_in, const int* in_sizes, int n_in,
                              void* d_out, int out_size, void* d_ws, size_t ws_size,
                              hipStream_t stream)
{
    const float* h    = (const float*)d_in[0];
    const float* W    = (const float*)d_in[1];
    const float* a    = (const float*)d_in[2];
    const float* W_ih = (const float*)d_in[3];
    const float* W_hh = (const float*)d_in[4];
    const float* b_ih = (const float*)d_in[5];
    const float* b_hh = (const float*)d_in[6];
    const int*   src  = (const int*)d_in[7];
    const int*   dst  = (const int*)d_in[8];
    float* out = (float*)d_out;

    char* ws = (char*)d_ws;
    size_t off = 0;
    auto alloc = [&](size_t bytes) { void* p = ws + off; off += (bytes + 255) & ~(size_t)255; return p; };

    u16*   hagg = (u16*)alloc((size_t)N_NODES * 512 * 2);
    float* gi   = (float*)alloc((size_t)N_NODES * 384 * 4);
    float* gh   = (float*)alloc((size_t)N_NODES * 384 * 4);
    u16*   hbf  = (u16*)alloc((size_t)N_NODES * 128 * 2);
    u16*   Wihb = (u16*)alloc(384 * 512 * 2);
    u16*   Whhb = (u16*)alloc(384 * 128 * 2);
    u16*   Wb   = (u16*)alloc(HEADS * 128 * 128 * 2);
    u16*   Mt   = (u16*)alloc(384 * 512 * 2);
    float* wa1  = (float*)alloc(512 * 4);
    float* wa2  = (float*)alloc(512 * 4);
    float* s_src = (float*)alloc((size_t)N_NODES * HEADS * 4);
    float* s_dst = (float*)alloc((size_t)N_NODES * HEADS * 4);
    int*   deg  = (int*)alloc((N_NODES + 1) * 4);
    int*   offs = (int*)alloc((N_NODES + 1) * 4);
    int*   cur  = (int*)alloc(N_NODES * 4);
    int*   ssort = (int*)alloc((size_t)E_EDGES * 4);

    hipMemsetAsync(deg, 0, N_NODES * sizeof(int), stream);

    cvt3_kernel<<<(384 * 512 + 255) / 256, 256, 0, stream>>>(
        W_ih, Wihb, 384 * 512, W_hh, Whhb, 384 * 128, W, Wb, HEADS * 128 * 128);
    wa_kernel<<<2, 256, 0, stream>>>(W, a, wa1, wa2);
    s_kernel<<<N_NODES, 256, 0, stream>>>(h, wa1, wa2, s_src, s_dst, hbf);

    deg_kernel<<<(E_EDGES + 255) / 256, 256, 0, stream>>>(dst, deg);
    scan_kernel<<<1, 1024, 0, stream>>>(deg, offs, cur);
    scatter_kernel<<<(E_EDGES + 255) / 256, 256, 0, stream>>>(src, dst, cur, ssort);

    // Mt (384 x 512 bf16): per head h, Mt[j][h*128+d] = sum_e W_ih[j][h*128+e] * W[h][d][e]
    gemm_bt<1><<<dim3(1, 3, 4), 256, 0, stream>>>(
        Wihb, Wb, Mt, 128, 512, 128, 512, 128L, 16384L, 128L);

    aggregate_kernel<<<N_NODES, 256, 0, stream>>>(
        (const u32*)hbf, s_src, s_dst, offs, ssort, hagg);

    // gi (16000x384) = hagg (16000x512) @ Mt(384x512)^T, f32 out
    gemm_bt<0><<<dim3(3, 125, 1), 256, 0, stream>>>(
        hagg, Mt, gi, 512, 512, 512, 384, 0L, 0L, 0L);
    // gh (16000x384) = hbf (16000x128) @ W_hh(384x128)^T, f32 out
    gemm_bt<0><<<dim3(3, 125, 1), 256, 0, stream>>>(
        hbf, Whhb, gh, 128, 128, 128, 384, 0L, 0L, 0L);

    gru_kernel<<<(N_NODES * DIM + 255) / 256, 256, 0, stream>>>(gi, gh, b_ih, b_hh, h, out);
}

// Round 4
// 196.980 us; speedup vs baseline: 2.1087x; 1.0648x over previous
//
#include <hip/hip_runtime.h>
#include <math.h>

#define N_NODES 16000
#define E_EDGES 256000
#define DIM 128
#define HEADS 4
#define LRELU_ALPHA 0.2f

typedef unsigned short u16;
typedef unsigned int u32;
typedef short bf16x8 __attribute__((ext_vector_type(8)));
typedef float floatx4 __attribute__((ext_vector_type(4)));

#define AS1 __attribute__((address_space(1)))
#define AS3 __attribute__((address_space(3)))

__device__ __forceinline__ u16 f2bf(float f) {
    u32 u = __float_as_uint(f);
    u32 r = (u + 0x7fffu + ((u >> 16) & 1u)) >> 16;   // RNE
    return (u16)r;
}
__device__ __forceinline__ float bflo(u32 v) { return __uint_as_float(v << 16); }
__device__ __forceinline__ float bfhi(u32 v) { return __uint_as_float(v & 0xffff0000u); }
__device__ __forceinline__ float bfs(u16 v) { return __uint_as_float((u32)v << 16); }

// ---------- wa[h][k] = sum_e W[h][k][e] * a{1,2}[h][e] ----------
__global__ void wa_kernel(const float* __restrict__ W, const float* __restrict__ a,
                          float* __restrict__ wa1, float* __restrict__ wa2)
{
    int t = blockIdx.x * blockDim.x + threadIdx.x;
    if (t >= HEADS * DIM) return;
    int h = t >> 7;
    const float* wrow = W + (long)t * DIM;
    const float* a1 = a + h * 2 * DIM;
    const float* a2 = a1 + DIM;
    float s1 = 0.f, s2 = 0.f;
    for (int e = 0; e < DIM; ++e) {
        float w = wrow[e];
        s1 = fmaf(w, a1[e], s1);
        s2 = fmaf(w, a2[e], s2);
    }
    wa1[t] = s1;
    wa2[t] = s2;
}

// ---------- fused prep: s-scores + h->bf16 into xcat | deg histogram | weight casts ----------
// blocks [0,16000): per-node scores + hbf;  [16000,17000): deg;  [17000,17768): casts
__global__ __launch_bounds__(256) void prep_kernel(
    const float* __restrict__ hin, const float* __restrict__ wa1, const float* __restrict__ wa2,
    const float* __restrict__ W_ih, const float* __restrict__ W,
    const int* __restrict__ dst,
    float* __restrict__ s_src, float* __restrict__ s_dst,
    u16* __restrict__ xcat, u16* __restrict__ Wihb, u16* __restrict__ Wb,
    int* __restrict__ deg)
{
    const int b = blockIdx.x;
    const int tid = threadIdx.x;
    if (b < N_NODES) {
        const int n = b;
        const int hh = tid >> 6;
        const int lane = tid & 63;
        float h0 = hin[(long)n * DIM + lane];
        float h1 = hin[(long)n * DIM + 64 + lane];
        if (hh == 0) {
            xcat[(size_t)n * 640 + 512 + lane] = f2bf(h0);
            xcat[(size_t)n * 640 + 576 + lane] = f2bf(h1);
        }
        const float* w1 = wa1 + hh * DIM;
        const float* w2 = wa2 + hh * DIM;
        float p = h0 * w1[lane] + h1 * w1[64 + lane];
        float q = h0 * w2[lane] + h1 * w2[64 + lane];
        #pragma unroll
        for (int off = 32; off > 0; off >>= 1) {
            p += __shfl_down(p, off, 64);
            q += __shfl_down(q, off, 64);
        }
        if (lane == 0) { s_src[n * HEADS + hh] = p; s_dst[n * HEADS + hh] = q; }
    } else if (b < N_NODES + 1000) {
        int e = (b - N_NODES) * 256 + tid;
        atomicAdd(&deg[dst[e]], 1);
    } else {
        int i = (b - N_NODES - 1000) * 256 + tid;   // [0, 196608)
        Wihb[i] = f2bf(W_ih[i]);
        if (i < HEADS * DIM * DIM) Wb[i] = f2bf(W[i]);
    }
}

// ---------- single-pass scan: 1024 threads x 16 elems ----------
__global__ __launch_bounds__(1024) void scan_kernel(const int* __restrict__ deg,
    int* __restrict__ offsets, int* __restrict__ cursor)
{
    __shared__ int wsum[16];
    const int tid = threadIdx.x;
    const int lane = tid & 63;
    const int w = tid >> 6;
    const int4* d4 = (const int4*)deg;
    int v[16];
    int tot = 0;
    #pragma unroll
    for (int i = 0; i < 4; ++i) {
        int i4 = tid * 4 + i;
        int4 vv = (i4 < N_NODES / 4) ? d4[i4] : int4{0, 0, 0, 0};
        v[i * 4 + 0] = vv.x; v[i * 4 + 1] = vv.y; v[i * 4 + 2] = vv.z; v[i * 4 + 3] = vv.w;
        tot += vv.x + vv.y + vv.z + vv.w;
    }
    int x = tot;
    #pragma unroll
    for (int off = 1; off < 64; off <<= 1) {
        int t = __shfl_up(x, off, 64);
        if (lane >= off) x += t;
    }
    if (lane == 63) wsum[w] = x;
    __syncthreads();
    if (w == 0) {
        int s = (lane < 16) ? wsum[lane] : 0;
        #pragma unroll
        for (int off = 1; off < 16; off <<= 1) {
            int t = __shfl_up(s, off, 64);
            if (lane >= off) s += t;
        }
        if (lane < 16) wsum[lane] = s;
    }
    __syncthreads();
    int excl = x - tot + ((w == 0) ? 0 : wsum[w - 1]);
    #pragma unroll
    for (int i = 0; i < 4; ++i) {
        int i4 = tid * 4 + i;
        if (i4 < N_NODES / 4) {
            int4 o;
            o.x = excl;
            o.y = excl + v[i * 4];
            o.z = o.y + v[i * 4 + 1];
            o.w = o.z + v[i * 4 + 2];
            ((int4*)offsets)[i4] = o;
            ((int4*)cursor)[i4] = o;
            excl = o.w + v[i * 4 + 3];
        }
    }
    if (tid == 1023) offsets[N_NODES] = excl;
}

// ---------- scatter edges into CSR | pack Wcat tail columns + zero rows ----------
// blocks [0,1000): scatter;  [1000,1512): pack
__global__ __launch_bounds__(256) void scatter_pack_kernel(
    const int* __restrict__ src, const int* __restrict__ dst,
    int* __restrict__ cursor, int* __restrict__ ssorted,
    const float* __restrict__ W_hh, u16* __restrict__ Wcat)
{
    const int b = blockIdx.x;
    const int tid = threadIdx.x;
    if (b < 1000) {
        int e = b * 256 + tid;
        int pos = atomicAdd(&cursor[dst[e]], 1);
        ssorted[pos] = src[e];
    } else {
        int t = (b - 1000) * 256 + tid;
        if (t < 65536) {
            int j = t >> 7, e = t & 127;
            u16 val;
            if (j < 256)      val = f2bf(W_hh[j * 128 + e]);
            else if (j < 384) val = 0;
            else              val = f2bf(W_hh[(j - 128) * 128 + e]);
            Wcat[(size_t)j * 640 + 512 + e] = val;
        } else {
            int t2 = t - 65536;
            int j = 384 + (t2 >> 9), c = t2 & 511;
            Wcat[(size_t)j * 640 + c] = 0;
        }
    }
}

// ---------- bf16 MFMA TN GEMM: C(R x C) = A(R x K) * Bt(C x K)^T ----------
__global__ __launch_bounds__(256) void gemm_bt(
    const u16* __restrict__ A, const u16* __restrict__ Bt, u16* __restrict__ C,
    int K, int lda, int ldb, int ldc,
    long a_zoff, long b_zoff, long c_zoff)
{
    A  += (long)blockIdx.z * a_zoff;
    Bt += (long)blockIdx.z * b_zoff;
    __shared__ __align__(16) u16 Alds[128][32];
    __shared__ __align__(16) u16 Blds[128][32];
    const int tid  = threadIdx.x;
    const int wave = tid >> 6;
    const int lane = tid & 63;
    const int quad = lane >> 4;
    const int l15  = lane & 15;
    const int row0 = blockIdx.y * 128;
    const int col0 = blockIdx.x * 128;
    const int wm = (wave >> 1) * 64;
    const int wn = (wave & 1) * 64;
    const int ch0 = wave * 2;
    const int srow = lane >> 2;
    const int scol = (lane & 3) * 8;

    floatx4 acc[4][4] = {};

    for (int k0 = 0; k0 < K; k0 += 32) {
        #pragma unroll
        for (int c = 0; c < 2; ++c) {
            int ch = ch0 + c;
            const u16* ga = A + (size_t)(row0 + ch * 16 + srow) * lda + k0 + scol;
            __builtin_amdgcn_global_load_lds((AS1 void*)ga, (AS3 void*)&Alds[ch * 16][0], 16, 0, 0);
            const u16* gb = Bt + (size_t)(col0 + ch * 16 + srow) * ldb + k0 + scol;
            __builtin_amdgcn_global_load_lds((AS1 void*)gb, (AS3 void*)&Blds[ch * 16][0], 16, 0, 0);
        }
        __syncthreads();
        bf16x8 af[4], bfr[4];
        #pragma unroll
        for (int i = 0; i < 4; ++i) af[i] = *(const bf16x8*)&Alds[wm + i * 16 + l15][quad * 8];
        #pragma unroll
        for (int j = 0; j < 4; ++j) bfr[j] = *(const bf16x8*)&Blds[wn + j * 16 + l15][quad * 8];
        #pragma unroll
        for (int i = 0; i < 4; ++i)
            #pragma unroll
            for (int j = 0; j < 4; ++j)
                acc[i][j] = __builtin_amdgcn_mfma_f32_16x16x32_bf16(af[i], bfr[j], acc[i][j], 0, 0, 0);
        __syncthreads();
    }
    #pragma unroll
    for (int i = 0; i < 4; ++i) {
        #pragma unroll
        for (int r = 0; r < 4; ++r) {
            int row = row0 + wm + i * 16 + quad * 4 + r;
            size_t base = (size_t)row * ldc + col0 + wn + l15 + (size_t)blockIdx.z * c_zoff;
            #pragma unroll
            for (int j = 0; j < 4; ++j) C[base + j * 16] = f2bf(acc[i][j][r]);
        }
    }
}

// ---------- fused softmax + h-gather aggregation (dedup loads, 4-way edge slices) ----------
__global__ __launch_bounds__(256) void aggregate_kernel(
    const float* __restrict__ s_src, const float* __restrict__ s_dst,
    const int* __restrict__ offsets, const int* __restrict__ srcs,
    u16* __restrict__ xcat)
{
    const int n = blockIdx.x;
    const int tid = threadIdx.x;
    const int start = offsets[n];
    const int deg = offsets[n + 1] - start;
    u32* xrow = (u32*)(xcat + (size_t)n * 640);
    if (deg == 0) { xrow[tid] = 0u; return; }

    __shared__ float sdst4[HEADS];
    __shared__ __align__(16) float attw[64][4];
    __shared__ int ssrc[64];
    __shared__ float redf[256];
    __shared__ float2 red2[256][4];

    if (tid < HEADS) sdst4[tid] = s_dst[n * HEADS + tid];
    __syncthreads();

    const int e4 = tid >> 6;
    const int dw = tid & 63;
    const int j  = tid >> 2;
    const int hh = tid & 3;
    const u32* hb = (const u32*)xcat;   // gather h-slice: row s dwords [s*320+256, s*320+320)

    float2 acc[4] = {{0.f,0.f},{0.f,0.f},{0.f,0.f},{0.f,0.f}};
    float dsum = 0.f;

    for (int cb = 0; cb < deg; cb += 64) {
        int clen = min(64, deg - cb);
        if (tid < clen) ssrc[tid] = srcs[start + cb + tid];
        __syncthreads();
        if (j < clen) {
            int s = ssrc[j];
            float e = s_src[s * HEADS + hh] + sdst4[hh];
            e = e > 0.f ? e : LRELU_ALPHA * e;
            float wv = __expf(e);
            attw[j][hh] = wv;
            dsum += wv;
        }
        __syncthreads();
        for (int jj = e4; jj < clen; jj += 4) {
            int s = ssrc[jj];
            u32 v = hb[s * 320 + 256 + dw];
            float lo = bflo(v), hi = bfhi(v);
            float4 wv = *(const float4*)attw[jj];
            acc[0].x = fmaf(wv.x, lo, acc[0].x); acc[0].y = fmaf(wv.x, hi, acc[0].y);
            acc[1].x = fmaf(wv.y, lo, acc[1].x); acc[1].y = fmaf(wv.y, hi, acc[1].y);
            acc[2].x = fmaf(wv.z, lo, acc[2].x); acc[2].y = fmaf(wv.z, hi, acc[2].y);
            acc[3].x = fmaf(wv.w, lo, acc[3].x); acc[3].y = fmaf(wv.w, hi, acc[3].y);
        }
        __syncthreads();
    }
    redf[tid] = dsum;
    __syncthreads();
    for (int off = 128; off >= 4; off >>= 1) {
        if (tid < off) redf[tid] += redf[tid + off];
        __syncthreads();
    }
    #pragma unroll
    for (int hq = 0; hq < 4; ++hq) red2[tid][hq] = acc[hq];
    __syncthreads();
    const int ho = tid >> 6, dwo = tid & 63;
    float invd = 1.f / redf[ho];
    float lo = 0.f, hi = 0.f;
    #pragma unroll
    for (int e = 0; e < 4; ++e) {
        float2 t = red2[e * 64 + dwo][ho];
        lo += t.x; hi += t.y;
    }
    xrow[tid] = (u32)f2bf(lo * invd) | ((u32)f2bf(hi * invd) << 16);
}

// ---------- GRU elementwise (bf16 gates: [r_sum | z_sum | i_n | h_n]) ----------
__global__ void gru_kernel(const u16* __restrict__ g,
                           const float* __restrict__ b_ih, const float* __restrict__ b_hh,
                           const float* __restrict__ hin, float* __restrict__ out)
{
    int idx = blockIdx.x * blockDim.x + threadIdx.x;
    if (idx >= N_NODES * DIM) return;
    int n = idx >> 7, d = idx & 127;
    const u16* gr = g + (size_t)n * 512;
    float A  = bfs(gr[d])       + b_ih[d]       + b_hh[d];
    float B  = bfs(gr[128 + d]) + b_ih[128 + d] + b_hh[128 + d];
    float Cn = bfs(gr[256 + d]) + b_ih[256 + d];
    float Dn = bfs(gr[384 + d]) + b_hh[256 + d];
    float r = 1.f / (1.f + __expf(-A));
    float z = 1.f / (1.f + __expf(-B));
    float pre = Cn + r * Dn;
    float e2 = __expf(2.f * pre);
    float nv = (e2 - 1.f) / (e2 + 1.f);
    out[idx] = (1.f - z) * nv + z * hin[idx];
}

extern "C" void kernel_launch(void* const* d_in, const int* in_sizes, int n_in,
                              void* d_out, int out_size, void* d_ws, size_t ws_size,
                              hipStream_t stream)
{
    const float* h    = (const float*)d_in[0];
    const float* W    = (const float*)d_in[1];
    const float* a    = (const float*)d_in[2];
    const float* W_ih = (const float*)d_in[3];
    const float* W_hh = (const float*)d_in[4];
    const float* b_ih = (const float*)d_in[5];
    const float* b_hh = (const float*)d_in[6];
    const int*   src  = (const int*)d_in[7];
    const int*   dst  = (const int*)d_in[8];
    float* out = (float*)d_out;

    char* ws = (char*)d_ws;
    size_t off = 0;
    auto alloc = [&](size_t bytes) { void* p = ws + off; off += (bytes + 255) & ~(size_t)255; return p; };

    u16*   xcat = (u16*)alloc((size_t)N_NODES * 640 * 2);   // [hagg(512) | hbf(128)]
    u16*   g    = (u16*)alloc((size_t)N_NODES * 512 * 2);   // [r_sum | z_sum | i_n | h_n]
    u16*   Wihb = (u16*)alloc(384 * 512 * 2);
    u16*   Wb   = (u16*)alloc(HEADS * 128 * 128 * 2);
    u16*   Wcat = (u16*)alloc(512 * 640 * 2);
    float* wa1  = (float*)alloc(512 * 4);
    float* wa2  = (float*)alloc(512 * 4);
    float* s_src = (float*)alloc((size_t)N_NODES * HEADS * 4);
    float* s_dst = (float*)alloc((size_t)N_NODES * HEADS * 4);
    int*   deg  = (int*)alloc((N_NODES + 1) * 4);
    int*   offs = (int*)alloc((N_NODES + 1) * 4);
    int*   cur  = (int*)alloc(N_NODES * 4);
    int*   ssort = (int*)alloc((size_t)E_EDGES * 4);

    hipMemsetAsync(deg, 0, (N_NODES + 1) * sizeof(int), stream);

    wa_kernel<<<2, 256, 0, stream>>>(W, a, wa1, wa2);

    // scores + hbf->xcat | deg | casts
    prep_kernel<<<N_NODES + 1000 + 768, 256, 0, stream>>>(
        h, wa1, wa2, W_ih, W, dst, s_src, s_dst, xcat, Wihb, Wb, deg);

    scan_kernel<<<1, 1024, 0, stream>>>(deg, offs, cur);

    // Wcat[:384][0:512] = Mt: per head z, Mt[j][z*128+d] = sum_e W_ih[j][z*128+e]*W[z][d][e]
    gemm_bt<<<dim3(1, 3, 4), 256, 0, stream>>>(
        Wihb, Wb, Wcat, 128, 512, 128, 640, 128L, 16384L, 128L);

    scatter_pack_kernel<<<1512, 256, 0, stream>>>(src, dst, cur, ssort, W_hh, Wcat);

    aggregate_kernel<<<N_NODES, 256, 0, stream>>>(s_src, s_dst, offs, ssort, xcat);

    // g (16000x512) = xcat (16000x640) @ Wcat(512x640)^T
    gemm_bt<<<dim3(4, 125, 1), 256, 0, stream>>>(
        xcat, Wcat, g, 640, 640, 640, 512, 0L, 0L, 0L);

    gru_kernel<<<(N_NODES * DIM + 255) / 256, 256, 0, stream>>>(g, b_ih, b_hh, h, out);
}